// Round 1
// baseline (103.199 us; speedup 1.0000x reference)
//
#include <hip/hip_runtime.h>
#include <math.h>

#define NFRM 8
#define A_NUM 8732
#define O_NUM 32
#define NEGPOS 3

// one block per (batch, frame); 512 threads
__global__ __launch_bounds__(512) void mfbl_frame_kernel(
    const float* __restrict__ loc_data,   // [BF, A, 4]
    const float* __restrict__ conf_data,  // [BF, A, 2]
    const float* __restrict__ anchors,    // [A, 4] center form
    const float* __restrict__ targets,    // [BF, O, 5]
    float* __restrict__ ws, int BF)       // ws[0..BF): loss_l, ws[BF..2BF): loss_c
{
#pragma clang fp contract(off)
    const int frame = blockIdx.x;
    const int tid = threadIdx.x;
    const int nthr = blockDim.x;
    const int lane = tid & 63;
    const int wid  = tid >> 6;

    __shared__ float s_tx1[O_NUM], s_ty1[O_NUM], s_tx2[O_NUM], s_ty2[O_NUM];
    __shared__ float s_area[O_NUM], s_lab[O_NUM];
    __shared__ float s_best_ov[A_NUM];
    __shared__ unsigned char s_best_o[A_NUM];
    __shared__ int s_bp[O_NUM];
    __shared__ float s_red_ov[O_NUM][8];
    __shared__ int   s_red_ix[O_NUM][8];
    __shared__ float s_rl[8], s_rc[8];
    __shared__ int   s_rnp[8], s_rm[8];

    // load truths for this frame
    if (tid < O_NUM) {
        const float* t = targets + ((size_t)frame * O_NUM + tid) * 5;
        float x1 = t[0], y1 = t[1], x2 = t[2], y2 = t[3];
        s_tx1[tid] = x1; s_ty1[tid] = y1; s_tx2[tid] = x2; s_ty2[tid] = y2;
        s_area[tid] = (x2 - x1) * (y2 - y1);
        s_lab[tid] = t[4];
    }
    __syncthreads();

    // ---------- pass 1: IoU, per-anchor best truth + per-truth best anchor ----------
    float tb_ov[O_NUM];
    int   tb_ix[O_NUM];
#pragma unroll
    for (int o = 0; o < O_NUM; ++o) { tb_ov[o] = -1.0f; tb_ix[o] = 0x7fffffff; }

    for (int a = tid; a < A_NUM; a += nthr) {
        const float4 pr = *(const float4*)(anchors + (size_t)a * 4);
        float px1 = pr.x - pr.z * 0.5f;
        float py1 = pr.y - pr.w * 0.5f;
        float px2 = pr.x + pr.z * 0.5f;
        float py2 = pr.y + pr.w * 0.5f;
        float area_p = (px2 - px1) * (py2 - py1);
        float best = -1.0f; int besto = 0;
#pragma unroll
        for (int o = 0; o < O_NUM; ++o) {
            float ltx = fmaxf(s_tx1[o], px1);
            float lty = fmaxf(s_ty1[o], py1);
            float rbx = fminf(s_tx2[o], px2);
            float rby = fminf(s_ty2[o], py2);
            float w = fmaxf(rbx - ltx, 0.0f);
            float h = fmaxf(rby - lty, 0.0f);
            float inter = w * h;
            float iou = inter / (s_area[o] + area_p - inter);
            if (iou > best) { best = iou; besto = o; }            // first-max over truths
            if (iou > tb_ov[o]) { tb_ov[o] = iou; tb_ix[o] = a; } // first-max over anchors (ties -> min idx via merge)
        }
        s_best_ov[a] = best;
        s_best_o[a]  = (unsigned char)besto;
    }

    // per-truth argmax reduce across block (tie-break: min anchor index)
#pragma unroll
    for (int o = 0; o < O_NUM; ++o) {
        float ov = tb_ov[o]; int ix = tb_ix[o];
        for (int s = 32; s > 0; s >>= 1) {
            float ov2 = __shfl_down(ov, s);
            int   ix2 = __shfl_down(ix, s);
            if (ov2 > ov || (ov2 == ov && ix2 < ix)) { ov = ov2; ix = ix2; }
        }
        if (lane == 0) { s_red_ov[o][wid] = ov; s_red_ix[o][wid] = ix; }
    }
    __syncthreads();
    if (tid < O_NUM) {
        float ov = s_red_ov[tid][0]; int ix = s_red_ix[tid][0];
        for (int w = 1; w < 8; ++w) {
            float ov2 = s_red_ov[tid][w]; int ix2 = s_red_ix[tid][w];
            if (ov2 > ov || (ov2 == ov && ix2 < ix)) { ov = ov2; ix = ix2; }
        }
        s_bp[tid] = ix;
    }
    __syncthreads();

    // ---------- pass 2: conf_t, losses ----------
    const float LOGEPS = -27.631021115928547f;  // log(1e-12)
    float l_sum = 0.0f, cpos = 0.0f;
    int np_cnt = 0, m_cnt = 0;

    for (int a = tid; a < A_NUM; a += nthr) {
        float ov = s_best_ov[a];
        int o = (int)s_best_o[a];
        int forced = -1;
#pragma unroll
        for (int t = 0; t < O_NUM; ++t)
            if (s_bp[t] == a) forced = t;   // last truth wins (scatter last-write)
        int conf;
        if (forced >= 0) { o = forced; conf = (int)s_lab[o] + 1; }
        else             { conf = (ov < 0.5f) ? 0 : ((int)s_lab[o] + 1); }

        const float2 cd = *(const float2*)(conf_data + ((size_t)frame * A_NUM + a) * 2);
        int pred = (cd.y > cd.x) ? 1 : 0;   // argmax, first occurrence on ties

        if (conf > 0) {
            np_cnt++;
            const float4 pr = *(const float4*)(anchors + (size_t)a * 4);
            const float4 ld = *(const float4*)(loc_data + ((size_t)frame * A_NUM + a) * 4);
            float x1 = s_tx1[o], y1 = s_ty1[o], x2 = s_tx2[o], y2 = s_ty2[o];
            float gx = ((x1 + x2) * 0.5f - pr.x) / (0.1f * pr.z);
            float gy = ((y1 + y2) * 0.5f - pr.y) / (0.1f * pr.w);
            float gw = logf((x2 - x1) / pr.z) / 0.2f;
            float gh = logf((y2 - y1) / pr.w) / 0.2f;
            float d0 = ld.x - gx, d1 = ld.y - gy, d2 = ld.z - gw, d3 = ld.w - gh;
            float a0 = fabsf(d0), a1 = fabsf(d1), a2 = fabsf(d2), a3 = fabsf(d3);
            float s0 = (a0 < 1.0f) ? 0.5f * d0 * d0 : a0 - 0.5f;
            float s1 = (a1 < 1.0f) ? 0.5f * d1 * d1 : a1 - 0.5f;
            float s2 = (a2 < 1.0f) ? 0.5f * d2 * d2 : a2 - 0.5f;
            float s3 = (a3 < 1.0f) ? 0.5f * d3 * d3 : a3 - 0.5f;
            l_sum += s0 + s1 + s2 + s3;
            // BCE for positive anchor (general tgt)
            float tgt = (float)conf;
            float logp   = (pred == 0) ? LOGEPS : 0.0f;
            float log1mp = (pred == 1) ? LOGEPS : 0.0f;
            cpos += -(tgt * logp + (1.0f - tgt) * log1mp);
        } else {
            m_cnt += pred;  // negatives with lc > log2  <=>  pred==1
        }
    }

    // block reduce the four scalars
    for (int s = 32; s > 0; s >>= 1) {
        l_sum  += __shfl_down(l_sum, s);
        cpos   += __shfl_down(cpos, s);
        np_cnt += __shfl_down(np_cnt, s);
        m_cnt  += __shfl_down(m_cnt, s);
    }
    if (lane == 0) { s_rl[wid] = l_sum; s_rc[wid] = cpos; s_rnp[wid] = np_cnt; s_rm[wid] = m_cnt; }
    __syncthreads();
    if (tid == 0) {
        float L = 0.0f, C = 0.0f; int np = 0, m = 0;
        for (int w = 0; w < 8; ++w) { L += s_rl[w]; C += s_rc[w]; np += s_rnp[w]; m += s_rm[w]; }
        int num_neg = min(NEGPOS * np, A_NUM - 1);
        int nsel = min(num_neg, m);   // selected negatives that are mispredicted
        ws[frame]      = L;
        ws[BF + frame] = C + 27.631021115928547f * (float)nsel;
    }
}

__global__ void mfbl_reduce_kernel(const float* __restrict__ ws, float* __restrict__ out, int n) {
    int tid = threadIdx.x;
    float a = (tid < n) ? ws[tid] : 0.0f;
    float b = (tid < n) ? ws[n + tid] : 0.0f;
    for (int s = 32; s > 0; s >>= 1) {
        a += __shfl_down(a, s);
        b += __shfl_down(b, s);
    }
    __shared__ float sa[4], sb[4];
    int lane = tid & 63, wid = tid >> 6;
    if (lane == 0) { sa[wid] = a; sb[wid] = b; }
    __syncthreads();
    if (tid == 0) {
        float A = 0.0f, B = 0.0f;
        for (int w = 0; w < 4; ++w) { A += sa[w]; B += sb[w]; }
        out[0] = A;
        out[1] = B;
    }
}

extern "C" void kernel_launch(void* const* d_in, const int* in_sizes, int n_in,
                              void* d_out, int out_size, void* d_ws, size_t ws_size,
                              hipStream_t stream) {
    const float* loc     = (const float*)d_in[0];
    const float* conf    = (const float*)d_in[1];
    const float* anchors = (const float*)d_in[2];
    const float* targets = (const float*)d_in[3];
    float* out = (float*)d_out;
    float* ws  = (float*)d_ws;

    const int BF = in_sizes[3] / (O_NUM * 5);   // 32*8 = 256 frames

    mfbl_frame_kernel<<<BF, 512, 0, stream>>>(loc, conf, anchors, targets, ws, BF);
    mfbl_reduce_kernel<<<1, 256, 0, stream>>>(ws, out, BF);
}